// Round 12
// baseline (95.890 us; speedup 1.0000x reference)
//
#include <hip/hip_runtime.h>
#include <hip/hip_bf16.h>
#include <stdint.h>

typedef __bf16 bf16x8 __attribute__((ext_vector_type(8)));
typedef float f32x4 __attribute__((ext_vector_type(4)));

#define IMG 2048
#define DD 768
#define NM16 16384
#define NM32 4096
#define L16_OFF 16
#define L32_OFF (16 + NM16)

__device__ __forceinline__ unsigned short f2bu(float f) {
  __hip_bfloat16 h = __float2bfloat16(f);
  return *reinterpret_cast<unsigned short*>(&h);
}

__device__ __forceinline__ float b2f(unsigned short u) {
  union { float f; unsigned int i; } x;
  x.i = ((unsigned int)u) << 16;
  return x.f;
}

__device__ __forceinline__ void gload16(const __hip_bfloat16* g, const __hip_bfloat16* l) {
  auto gp = reinterpret_cast<const __attribute__((address_space(1))) unsigned int*>(
      reinterpret_cast<uintptr_t>(g));
  auto lp = reinterpret_cast<__attribute__((address_space(3))) unsigned int*>(
      reinterpret_cast<uintptr_t>(l));
  __builtin_amdgcn_global_load_lds(gp, lp, 16, 0, 0);
}

__device__ __forceinline__ unsigned long long mask_bits(const unsigned char* m, int cell0,
                                                        int ncell, int msize) {
  unsigned long long bits = 0;
  if (msize == 1) {
    const unsigned int* p = (const unsigned int*)(m + cell0);
#pragma unroll
    for (int i = 0; i < 16; ++i) {
      if (i >= ncell / 4) break;
      unsigned int v = p[i];
      bits |= (unsigned long long)((v & 0xFFu) != 0) << (4 * i);
      bits |= (unsigned long long)((v & 0xFF00u) != 0) << (4 * i + 1);
      bits |= (unsigned long long)((v & 0xFF0000u) != 0) << (4 * i + 2);
      bits |= (unsigned long long)((v >> 24) != 0) << (4 * i + 3);
    }
  } else if (msize == 4) {
    const uint4* p = (const uint4*)(m + (size_t)cell0 * 4);
#pragma unroll
    for (int i = 0; i < 16; ++i) {
      if (i >= ncell / 4) break;
      uint4 v = p[i];
      bits |= (unsigned long long)(v.x != 0) << (4 * i);
      bits |= (unsigned long long)(v.y != 0) << (4 * i + 1);
      bits |= (unsigned long long)(v.z != 0) << (4 * i + 2);
      bits |= (unsigned long long)(v.w != 0) << (4 * i + 3);
    }
  } else {
    const uint4* p = (const uint4*)(m + (size_t)cell0 * 8);
#pragma unroll
    for (int i = 0; i < 32; ++i) {
      if (i >= ncell / 2) break;
      uint4 v = p[i];
      bits |= (unsigned long long)((v.x | v.y) != 0) << (2 * i);
      bits |= (unsigned long long)((v.z | v.w) != 0) << (2 * i + 1);
    }
  }
  return bits;
}

__device__ __forceinline__ float keys_w(float t) {
  t = fabsf(t);
  if (t <= 1.f) return ((1.5f * t - 2.5f) * t) * t + 1.f;
  if (t < 2.f) return ((-0.5f * t + 2.5f) * t - 4.f) * t + 2.f;
  return 0.f;
}

// =============== K1: prep | zc_scan | conv_w | pos_pass1 (fused, role by blockIdx) ========
__global__ __launch_bounds__(256) void k1_kernel(
    const unsigned char* __restrict__ m16, const unsigned char* __restrict__ m32,
    const float* __restrict__ cls, const float* __restrict__ pos,
    const float* __restrict__ proj_w, const float* __restrict__ zw,
    const float* __restrict__ zb, float* __restrict__ out, int out_size, int total,
    int* __restrict__ wsi, __hip_bfloat16* __restrict__ Wb,
    __hip_bfloat16* __restrict__ tmp) {
  __shared__ float shbuf[8192];                 // 32 KB union
  const int b = blockIdx.x;
  const int tid = threadIdx.x;

  if (b == 0) {
    int* sc = (int*)shbuf;
    int* sh_cnt = sc + 256;
    int* sh_msize = sc + 257;
    if (tid == 0) *sh_cnt = 0;
    __syncthreads();
    {
      uint4 v = ((const uint4*)m32)[tid];
      unsigned int w[4] = {v.x, v.y, v.z, v.w};
      int c = 0;
#pragma unroll
      for (int j = 0; j < 4; ++j)
#pragma unroll
        for (int bb = 0; bb < 4; ++bb) c += ((w[j] >> (8 * bb)) & 255u) != 0;
      atomicAdd(sh_cnt, c);
    }
    __syncthreads();
    if (tid == 0) { *sh_msize = (NM16 - 3 * *sh_cnt == total) ? 1 : 0; *sh_cnt = 0; }
    __syncthreads();
    if (*sh_msize == 0) {
      const uint4* p = (const uint4*)m32;
      int c = 0;
      for (int i = tid; i < 1024; i += 256) {
        uint4 v = p[i];
        c += (v.x != 0) + (v.y != 0) + (v.z != 0) + (v.w != 0);
      }
      atomicAdd(sh_cnt, c);
      __syncthreads();
      if (tid == 0) *sh_msize = (NM16 - 3 * *sh_cnt == total) ? 4 : 8;
      __syncthreads();
    }
    const int msize = *sh_msize;

    unsigned long long bits = mask_bits(m16, tid * 64, 64, msize);
    int cnt = __popcll(bits);
    sc[tid] = cnt;
    __syncthreads();
    for (int off = 1; off < 256; off <<= 1) {
      int v = (tid >= off) ? sc[tid - off] : 0;
      __syncthreads();
      sc[tid] += v;
      __syncthreads();
    }
    int n1 = sc[255];
    {
      int wp = L16_OFF + sc[tid] - cnt;
      unsigned long long bb = bits;
      while (bb) {
        int i = __ffsll((unsigned long long)bb) - 1;
        bb &= bb - 1;
        wsi[wp++] = tid * 64 + i;
      }
    }
    __syncthreads();
    bits = mask_bits(m32, tid * 16, 16, msize);
    cnt = __popcll(bits);
    sc[tid] = cnt;
    __syncthreads();
    for (int off = 1; off < 256; off <<= 1) {
      int v = (tid >= off) ? sc[tid - off] : 0;
      __syncthreads();
      sc[tid] += v;
      __syncthreads();
    }
    int n2 = sc[255];
    {
      int wp = L32_OFF + sc[tid] - cnt;
      unsigned long long bb = bits;
      while (bb) {
        int i = __ffsll((unsigned long long)bb) - 1;
        bb &= bb - 1;
        wsi[wp++] = tid * 16 + i;
      }
    }
    if (tid == 0) {
      wsi[0] = n1; wsi[1] = n2; wsi[2] = 0; wsi[3] = msize;
      out[out_size - 1] = (float)(n1 + n2);
    }
    for (int d = tid; d < DD; d += 256) out[d] = cls[d] + pos[d];
  } else if (b < 577) {
    int i = (b - 1) * 256 + tid;
    float4 v = ((const float4*)zw)[i];
    bool nz = (v.x != 0.f) | (v.y != 0.f) | (v.z != 0.f) | (v.w != 0.f);
    if (i < DD) nz |= (zb[i] != 0.f);
    if (__any(nz)) {
      if ((tid & 63) == 0) atomicOr(&wsi[2], 1);
    }
  } else if (b < 1153) {
    int i = (b - 577) * 256 + tid;
    float4 v = ((const float4*)proj_w)[i];
    ushort4 u;
    u.x = f2bu(v.x); u.y = f2bu(v.y); u.z = f2bu(v.z); u.w = f2bu(v.w);
    ((ushort4*)Wb)[i] = u;
  } else {
    // pos_pass1: j-direction bicubic conv, pos -> tmp
    int r = b - 1153;                 // [0,1536)
    int x = r / 12, chb = r % 12;
    int d0 = chb * 64;
    float (*lds)[64] = (float(*)[64])shbuf;     // [128][64]
    const float* src = pos + (size_t)(1 + x * 128) * DD + d0;
    for (int it = 0; it < 32; ++it) {
      int idx = it * 256 + tid;
      int y = idx >> 6, d = idx & 63;
      lds[y][d] = src[(size_t)y * DD + d];
    }
    __syncthreads();
    float wb[8];
#pragma unroll
    for (int bb = 0; bb < 8; ++bb) wb[bb] = keys_w(fabsf((float)bb - 3.5f) * 0.5f);
    const int d = tid & 63;
    const int jh = tid >> 6;          // 0..3
    for (int j2 = jh; j2 < 64; j2 += 4) {
      float nj = 0.f, s = 0.f;
#pragma unroll
      for (int bb = 0; bb < 8; ++bb) {
        int y = 2 * j2 - 3 + bb;
        if (y >= 0 && y < 128) { nj += wb[bb]; s += wb[bb] * lds[y][d]; }
      }
      tmp[((size_t)x * 64 + j2) * DD + d0 + d] = __float2bfloat16(s / nj);
    }
  }
}

// =============== K2: stage A rows + FULL Pbuf rows, grid = mpad rows, 192 threads =========
__global__ void k2_stage(const float* __restrict__ img, const int* __restrict__ wsi,
                         const float* __restrict__ pos, const __hip_bfloat16* __restrict__ tmp,
                         __hip_bfloat16* __restrict__ A, __hip_bfloat16* __restrict__ Pbuf,
                         int total, int useSep) {
  const int r = blockIdx.x;
  const int tid = threadIdx.x;            // 0..191
  if (r >= total) {
    ushort4 z = {0, 0, 0, 0};
    *(ushort4*)(A + (size_t)r * DD + tid * 4) = z;
    *(ushort4*)(Pbuf + (size_t)r * DD + tid * 4) = z;
    return;
  }
  const int n1 = wsi[0];
  // ---- A row (bf16 patch) ----
  {
    const int ch = tid >> 6;
    const int rem = tid & 63;
    const int h = rem >> 2;
    const int w4 = rem & 3;
    const int k = ch * 256 + h * 16 + w4 * 4;
    float o0, o1, o2, o3;
    if (r < n1) {
      int cell = wsi[L16_OFF + r];
      int gi = cell >> 7, gj = cell & 127;
      const float* p = img + ((size_t)(ch * IMG) + gi * 16 + h) * IMG + gj * 16 + w4 * 4;
      float4 v = *(const float4*)p;
      o0 = v.x; o1 = v.y; o2 = v.z; o3 = v.w;
    } else {
      int cell = wsi[L32_OFF + (r - n1)];
      int i2 = cell >> 6, j2 = cell & 63;
      const float* p = img + ((size_t)(ch * IMG) + i2 * 32 + h * 2) * IMG + j2 * 32 + w4 * 8;
      float4 a0 = *(const float4*)p;
      float4 a1 = *(const float4*)(p + 4);
      float4 b0 = *(const float4*)(p + IMG);
      float4 b1 = *(const float4*)(p + IMG + 4);
      o0 = 0.25f * (a0.x + a0.y + b0.x + b0.y);
      o1 = 0.25f * (a0.z + a0.w + b0.z + b0.w);
      o2 = 0.25f * (a1.x + a1.y + b1.x + b1.y);
      o3 = 0.25f * (a1.z + a1.w + b1.z + b1.w);
    }
    ushort4 u;
    u.x = f2bu(o0); u.y = f2bu(o1); u.z = f2bu(o2); u.w = f2bu(o3);
    *(ushort4*)(A + (size_t)r * DD + k) = u;
  }
  // ---- Pbuf row: pos16 gather (r<n1) | vertical bicubic from tmp (r>=n1, useSep) ----
  {
    const int d = tid * 4;
    ushort4 pb;
    if (r < n1) {
      int cell = wsi[L16_OFF + r];
      float4 v = *(const float4*)(pos + (size_t)(1 + cell) * DD + d);
      pb.x = f2bu(v.x); pb.y = f2bu(v.y); pb.z = f2bu(v.z); pb.w = f2bu(v.w);
    } else if (useSep) {
      int cell = wsi[L32_OFF + (r - n1)];
      int i2 = cell >> 6, j2 = cell & 63;
      float wi[8]; int xi[8]; float ni = 0.f;
#pragma unroll
      for (int a = 0; a < 8; ++a) {
        float wgt = keys_w(fabsf((float)a - 3.5f) * 0.5f);
        int x = 2 * i2 - 3 + a;
        bool v = (x >= 0 && x < 128);
        wi[a] = v ? wgt : 0.f; xi[a] = v ? x : 0; ni += wi[a];
      }
      float inv = 1.f / ni;
      float s0 = 0.f, s1 = 0.f, s2 = 0.f, s3 = 0.f;
#pragma unroll
      for (int a = 0; a < 8; ++a) {
        if (wi[a] == 0.f) continue;
        ushort4 u = *(const ushort4*)(tmp + ((size_t)xi[a] * 64 + j2) * DD + d);
        s0 += wi[a] * b2f(u.x); s1 += wi[a] * b2f(u.y);
        s2 += wi[a] * b2f(u.z); s3 += wi[a] * b2f(u.w);
      }
      pb.x = f2bu(s0 * inv); pb.y = f2bu(s1 * inv);
      pb.z = f2bu(s2 * inv); pb.w = f2bu(s3 * inv);
    } else {
      pb.x = 0; pb.y = 0; pb.z = 0; pb.w = 0;   // fallback: k4 adds pos32 directly
    }
    *(ushort4*)(Pbuf + (size_t)r * DD + d) = pb;
  }
}

// =============== K3: GEMM — 128x64 tile, 2 waves, 4-buf depth-2 counted vmcnt =============
// 948 blocks (~3.7/CU), LDS 48 KB (3 blocks/CU), 2-wave barrier groups.
// Per-wave per-step work identical to the proven R10 loop (8 ds_read_b128 + 16 MFMA).
__global__ __launch_bounds__(128) void gemm_kernel(
    const __hip_bfloat16* __restrict__ A, const __hip_bfloat16* __restrict__ Wb,
    const float* __restrict__ bias, const __hip_bfloat16* __restrict__ Pbuf,
    float* __restrict__ out, int M) {
  __shared__ __hip_bfloat16 As[4][128 * 32];   // 32 KB
  __shared__ __hip_bfloat16 Bs[4][64 * 32];    // 16 KB
  const int tid = threadIdx.x;
  const int lane = tid & 63, w = tid >> 6;     // w in {0,1}
  const int nwg = gridDim.x;
  const int orig = blockIdx.x;
  const int q = nwg >> 3, r8 = nwg & 7;
  const int xcd = orig & 7;
  const int wg = ((xcd < r8) ? xcd * (q + 1) : r8 * (q + 1) + (xcd - r8) * q) + (orig >> 3);
  const int bx = wg % 12;
  const int by = wg / 12;
  const int m0 = by * 128, n0 = bx * 64;
  f32x4 acc[4][4] = {};

  const int lrow = lane >> 2;            // 0..15
  const int lcol = (lane & 3) * 8;       // 16B chunks along K
  const __hip_bfloat16* gA = A + (size_t)(m0 + w * 64 + lrow) * DD + lcol;
  const __hip_bfloat16* gB = Wb + (size_t)(n0 + w * 32 + lrow) * DD + lcol;

#define STAGE(buf, kt)                                                \
  do {                                                                \
    gload16(gA + (kt) * 32, &As[buf][(w * 64) * 32]);                 \
    gload16(gA + 16 * DD + (kt) * 32, &As[buf][(w * 64 + 16) * 32]);  \
    gload16(gA + 32 * DD + (kt) * 32, &As[buf][(w * 64 + 32) * 32]);  \
    gload16(gA + 48 * DD + (kt) * 32, &As[buf][(w * 64 + 48) * 32]);  \
    gload16(gB + (kt) * 32, &Bs[buf][(w * 32) * 32]);                 \
    gload16(gB + 16 * DD + (kt) * 32, &Bs[buf][(w * 32 + 16) * 32]);  \
  } while (0)

#define COMPUTE(buf)                                                                         \
  do {                                                                                       \
    bf16x8 af[4], bfr[4];                                                                    \
    _Pragma("unroll") for (int f = 0; f < 4; ++f) {                                          \
      af[f] = *reinterpret_cast<const bf16x8*>(                                              \
          &As[buf][(w * 64 + f * 16 + (lane & 15)) * 32 + ((lane >> 4) << 3)]);              \
      bfr[f] = *reinterpret_cast<const bf16x8*>(                                             \
          &Bs[buf][(f * 16 + (lane & 15)) * 32 + ((lane >> 4) << 3)]);                       \
    }                                                                                        \
    _Pragma("unroll") for (int fm = 0; fm < 4; ++fm)                                         \
    _Pragma("unroll") for (int fn = 0; fn < 4; ++fn)                                         \
      acc[fm][fn] = __builtin_amdgcn_mfma_f32_16x16x32_bf16(af[fm], bfr[fn], acc[fm][fn],    \
                                                            0, 0, 0);                        \
  } while (0)

  // prologue: 2 tiles in flight (12 loads/wave)
  STAGE(0, 0);
  STAGE(1, 1);
  // main loop: stage kt+2, wait own tile (12 newer loads outstanding), barrier, compute.
  // 4 buffers -> reuse distance 4: race-free with one barrier/step (proven R4/R10).
#pragma unroll 1
  for (int kt = 0; kt < 22; ++kt) {
    STAGE((kt + 2) & 3, kt + 2);
    asm volatile("s_waitcnt vmcnt(12)" ::: "memory");
    __builtin_amdgcn_s_barrier();
    COMPUTE(kt & 3);
  }
  asm volatile("s_waitcnt vmcnt(6)" ::: "memory");
  __builtin_amdgcn_s_barrier();
  COMPUTE(2);
  asm volatile("s_waitcnt vmcnt(0)" ::: "memory");
  __builtin_amdgcn_s_barrier();
  COMPUTE(3);
#undef STAGE
#undef COMPUTE

#pragma unroll
  for (int fm = 0; fm < 4; ++fm) {
    int mbase = m0 + w * 64 + fm * 16 + ((lane >> 4) << 2);
#pragma unroll
    for (int r = 0; r < 4; ++r) {
      int m = mbase + r;
      if (m >= M) continue;
      const __hip_bfloat16* pp = Pbuf + (size_t)m * DD;
      float* po = out + (size_t)(1 + m) * DD;
#pragma unroll
      for (int fn = 0; fn < 4; ++fn) {
        int n = n0 + fn * 16 + (lane & 15);
        po[n] = acc[fm][fn][r] + bias[n] + b2f(*(const unsigned short*)(pp + n));
      }
    }
  }
}

// =============== K4: zc_path (honest, early-exit) [+ pos32_add fallback] ==================
__global__ __launch_bounds__(256) void k4_kernel(
    const float* __restrict__ pos, const int* __restrict__ wsi, float* __restrict__ out,
    int useSep, const float* __restrict__ img, const float* __restrict__ pw,
    const float* __restrict__ pb, const float* __restrict__ aw,
    const float* __restrict__ ab, const float* __restrict__ zw,
    const float* __restrict__ zb) {
  const int b = blockIdx.x;
  const int tid = threadIdx.x;
  const int n1 = wsi[0], n2 = wsi[1];
  const int zcb = useSep ? b : b - NM32;

  if (zcb < 0) {
    int r = b;
    if (r >= n2) return;
    int cell = wsi[L32_OFF + r];
    int i2 = cell >> 6, j2 = cell & 63;
    float wi[8], wj[8]; int xi[8], yj[8]; float ni = 0.f, nj = 0.f;
#pragma unroll
    for (int a = 0; a < 8; ++a) {
      float wgt = keys_w(fabsf((float)a - 3.5f) * 0.5f);
      int x = 2 * i2 - 3 + a;
      bool vx = (x >= 0 && x < 128);
      wi[a] = vx ? wgt : 0.f; xi[a] = vx ? x : 0; ni += wi[a];
      int y = 2 * j2 - 3 + a;
      bool vy = (y >= 0 && y < 128);
      wj[a] = vy ? wgt : 0.f; yj[a] = vy ? y : 0; nj += wj[a];
    }
    float inv = 1.f / (ni * nj);
#pragma unroll
    for (int it = 0; it < 3; ++it) {
      int d = it * 256 + tid;
      float s = 0.f;
#pragma unroll
      for (int a = 0; a < 8; ++a) {
        if (wi[a] == 0.f) continue;
        float si = 0.f;
#pragma unroll
        for (int bb = 0; bb < 8; ++bb) {
          if (wj[bb] == 0.f) continue;
          si += wj[bb] * pos[(size_t)(1 + xi[a] * 128 + yj[bb]) * DD + d];
        }
        s += wi[a] * si;
      }
      out[(size_t)(1 + n1 + r) * DD + d] += s * inv;
    }
  } else {
    if (wsi[2] == 0) return;
    int r = zcb;
    if (r >= n2) return;
    int cell = wsi[L32_OFF + r];
    int i2 = cell >> 6, j2 = cell & 63;
    __shared__ float patch[DD];
    __shared__ float ft[4][DD];
    __shared__ float attnv[DD];
    for (int qq = 0; qq < 4; ++qq) {
      int qh = qq >> 1, qw = qq & 1;
      int gi = 2 * i2 + qh, gj = 2 * j2 + qw;
      for (int it = 0; it < 3; ++it) {
        int k = tid + it * 256;
        int c = k >> 8, h = (k >> 4) & 15, ww = k & 15;
        patch[k] = img[(c * IMG + gi * 16 + h) * IMG + gj * 16 + ww];
      }
      __syncthreads();
      for (int it = 0; it < 3; ++it) {
        int e = tid + it * 256;
        float s = pb[e];
        for (int k = 0; k < DD; ++k) s += patch[k] * pw[(size_t)e * DD + k];
        ft[qq][e] = s;
      }
      __syncthreads();
    }
    for (int it = 0; it < 3; ++it) {
      int d = tid + it * 256;
      float s = ab[d];
      for (int e = 0; e < DD; ++e) {
        const float* awp = aw + ((size_t)d * DD + e) * 4;
        s += ft[0][e] * awp[0] + ft[1][e] * awp[1] + ft[2][e] * awp[2] + ft[3][e] * awp[3];
      }
      attnv[d] = s;
    }
    __syncthreads();
    for (int it = 0; it < 3; ++it) {
      int d = tid + it * 256;
      float s = zb[d];
      for (int e = 0; e < DD; ++e) s += attnv[e] * zw[(size_t)d * DD + e];
      out[(size_t)(1 + n1 + r) * DD + d] += s;
    }
  }
}

extern "C" void kernel_launch(void* const* d_in, const int* in_sizes, int n_in,
                              void* d_out, int out_size, void* d_ws, size_t ws_size,
                              hipStream_t stream) {
  const float* image = (const float*)d_in[0];
  const unsigned char* m16 = (const unsigned char*)d_in[1];
  const unsigned char* m32 = (const unsigned char*)d_in[2];
  const float* proj_w = (const float*)d_in[3];
  const float* proj_b = (const float*)d_in[4];
  const float* cls    = (const float*)d_in[5];
  const float* pos    = (const float*)d_in[6];
  const float* attn_w = (const float*)d_in[7];
  const float* attn_b = (const float*)d_in[8];
  const float* zc_w   = (const float*)d_in[9];
  const float* zc_b   = (const float*)d_in[10];
  float* out = (float*)d_out;

  const int total = (out_size - 1) / DD - 1;          // N1+N2, host-known
  const int mpad = ((total + 127) / 128) * 128;

  int* wsi = (int*)d_ws;
  const size_t offTmp = 82176;
  const size_t tmpB = (size_t)128 * 64 * DD * 2;       // 12.6 MB
  const size_t pbufB = (size_t)mpad * DD * 2;
  const size_t abufB = (size_t)mpad * DD * 2;
  const size_t wB = (size_t)DD * DD * 2;
  bool useSep;
  size_t offP;
  if (ws_size >= offTmp + tmpB + pbufB + abufB + wB) { useSep = true;  offP = offTmp + tmpB; }
  else if (ws_size >= offTmp + pbufB + abufB + wB)   { useSep = false; offP = offTmp; }
  else return;

  __hip_bfloat16* Tmp  = (__hip_bfloat16*)((char*)d_ws + offTmp);
  __hip_bfloat16* Pbuf = (__hip_bfloat16*)((char*)d_ws + offP);
  __hip_bfloat16* Abuf = (__hip_bfloat16*)((char*)d_ws + offP + pbufB);
  __hip_bfloat16* Wbuf = (__hip_bfloat16*)((char*)d_ws + offP + pbufB + abufB);

  int grid1 = 1153 + (useSep ? 1536 : 0);
  k1_kernel<<<grid1, 256, 0, stream>>>(m16, m32, cls, pos, proj_w, zc_w, zc_b, out,
                                       out_size, total, wsi, Wbuf, Tmp);
  k2_stage<<<mpad, 192, 0, stream>>>(image, wsi, pos, Tmp, Abuf, Pbuf, total,
                                     useSep ? 1 : 0);
  int gemm_grid = (mpad / 128) * 12;
  gemm_kernel<<<gemm_grid, 128, 0, stream>>>(Abuf, Wbuf, proj_b, Pbuf, out, total);
  k4_kernel<<<useSep ? NM32 : 2 * NM32, 256, 0, stream>>>(
      pos, wsi, out, useSep ? 1 : 0, image, proj_w, proj_b, attn_w, attn_b, zc_w, zc_b);
}

// Round 13
// 80.260 us; speedup vs baseline: 1.1947x; 1.1947x over previous
//
#include <hip/hip_runtime.h>
#include <hip/hip_bf16.h>
#include <stdint.h>

typedef __bf16 bf16x8 __attribute__((ext_vector_type(8)));
typedef float f32x4 __attribute__((ext_vector_type(4)));

#define IMG 2048
#define DD 768
#define NM16 16384
#define NM32 4096
#define L16_OFF 16
#define L32_OFF (16 + NM16)

__device__ __forceinline__ unsigned short f2bu(float f) {
  __hip_bfloat16 h = __float2bfloat16(f);
  return *reinterpret_cast<unsigned short*>(&h);
}

__device__ __forceinline__ float b2f(unsigned short u) {
  union { float f; unsigned int i; } x;
  x.i = ((unsigned int)u) << 16;
  return x.f;
}

__device__ __forceinline__ void gload16(const __hip_bfloat16* g, const __hip_bfloat16* l) {
  auto gp = reinterpret_cast<const __attribute__((address_space(1))) unsigned int*>(
      reinterpret_cast<uintptr_t>(g));
  auto lp = reinterpret_cast<__attribute__((address_space(3))) unsigned int*>(
      reinterpret_cast<uintptr_t>(l));
  __builtin_amdgcn_global_load_lds(gp, lp, 16, 0, 0);
}

__device__ __forceinline__ unsigned long long mask_bits(const unsigned char* m, int cell0,
                                                        int ncell, int msize) {
  unsigned long long bits = 0;
  if (msize == 1) {
    const unsigned int* p = (const unsigned int*)(m + cell0);
#pragma unroll
    for (int i = 0; i < 16; ++i) {
      if (i >= ncell / 4) break;
      unsigned int v = p[i];
      bits |= (unsigned long long)((v & 0xFFu) != 0) << (4 * i);
      bits |= (unsigned long long)((v & 0xFF00u) != 0) << (4 * i + 1);
      bits |= (unsigned long long)((v & 0xFF0000u) != 0) << (4 * i + 2);
      bits |= (unsigned long long)((v >> 24) != 0) << (4 * i + 3);
    }
  } else if (msize == 4) {
    const uint4* p = (const uint4*)(m + (size_t)cell0 * 4);
#pragma unroll
    for (int i = 0; i < 16; ++i) {
      if (i >= ncell / 4) break;
      uint4 v = p[i];
      bits |= (unsigned long long)(v.x != 0) << (4 * i);
      bits |= (unsigned long long)(v.y != 0) << (4 * i + 1);
      bits |= (unsigned long long)(v.z != 0) << (4 * i + 2);
      bits |= (unsigned long long)(v.w != 0) << (4 * i + 3);
    }
  } else {
    const uint4* p = (const uint4*)(m + (size_t)cell0 * 8);
#pragma unroll
    for (int i = 0; i < 32; ++i) {
      if (i >= ncell / 2) break;
      uint4 v = p[i];
      bits |= (unsigned long long)((v.x | v.y) != 0) << (2 * i);
      bits |= (unsigned long long)((v.z | v.w) != 0) << (2 * i + 1);
    }
  }
  return bits;
}

__device__ __forceinline__ float keys_w(float t) {
  t = fabsf(t);
  if (t <= 1.f) return ((1.5f * t - 2.5f) * t) * t + 1.f;
  if (t < 2.f) return ((-0.5f * t + 2.5f) * t - 4.f) * t + 2.f;
  return 0.f;
}

// =============== K1: prep | zc_scan | conv_w | pos_pass1 (fused, role by blockIdx) ========
__global__ __launch_bounds__(256) void k1_kernel(
    const unsigned char* __restrict__ m16, const unsigned char* __restrict__ m32,
    const float* __restrict__ cls, const float* __restrict__ pos,
    const float* __restrict__ proj_w, const float* __restrict__ zw,
    const float* __restrict__ zb, float* __restrict__ out, int out_size, int total,
    int* __restrict__ wsi, __hip_bfloat16* __restrict__ Wb,
    __hip_bfloat16* __restrict__ tmp) {
  __shared__ float shbuf[8192];                 // 32 KB union
  const int b = blockIdx.x;
  const int tid = threadIdx.x;

  if (b == 0) {
    int* sc = (int*)shbuf;
    int* sh_cnt = sc + 256;
    int* sh_msize = sc + 257;
    if (tid == 0) *sh_cnt = 0;
    __syncthreads();
    {
      uint4 v = ((const uint4*)m32)[tid];
      unsigned int w[4] = {v.x, v.y, v.z, v.w};
      int c = 0;
#pragma unroll
      for (int j = 0; j < 4; ++j)
#pragma unroll
        for (int bb = 0; bb < 4; ++bb) c += ((w[j] >> (8 * bb)) & 255u) != 0;
      atomicAdd(sh_cnt, c);
    }
    __syncthreads();
    if (tid == 0) { *sh_msize = (NM16 - 3 * *sh_cnt == total) ? 1 : 0; *sh_cnt = 0; }
    __syncthreads();
    if (*sh_msize == 0) {
      const uint4* p = (const uint4*)m32;
      int c = 0;
      for (int i = tid; i < 1024; i += 256) {
        uint4 v = p[i];
        c += (v.x != 0) + (v.y != 0) + (v.z != 0) + (v.w != 0);
      }
      atomicAdd(sh_cnt, c);
      __syncthreads();
      if (tid == 0) *sh_msize = (NM16 - 3 * *sh_cnt == total) ? 4 : 8;
      __syncthreads();
    }
    const int msize = *sh_msize;

    unsigned long long bits = mask_bits(m16, tid * 64, 64, msize);
    int cnt = __popcll(bits);
    sc[tid] = cnt;
    __syncthreads();
    for (int off = 1; off < 256; off <<= 1) {
      int v = (tid >= off) ? sc[tid - off] : 0;
      __syncthreads();
      sc[tid] += v;
      __syncthreads();
    }
    int n1 = sc[255];
    {
      int wp = L16_OFF + sc[tid] - cnt;
      unsigned long long bb = bits;
      while (bb) {
        int i = __ffsll((unsigned long long)bb) - 1;
        bb &= bb - 1;
        wsi[wp++] = tid * 64 + i;
      }
    }
    __syncthreads();
    bits = mask_bits(m32, tid * 16, 16, msize);
    cnt = __popcll(bits);
    sc[tid] = cnt;
    __syncthreads();
    for (int off = 1; off < 256; off <<= 1) {
      int v = (tid >= off) ? sc[tid - off] : 0;
      __syncthreads();
      sc[tid] += v;
      __syncthreads();
    }
    int n2 = sc[255];
    {
      int wp = L32_OFF + sc[tid] - cnt;
      unsigned long long bb = bits;
      while (bb) {
        int i = __ffsll((unsigned long long)bb) - 1;
        bb &= bb - 1;
        wsi[wp++] = tid * 16 + i;
      }
    }
    if (tid == 0) {
      wsi[0] = n1; wsi[1] = n2; wsi[2] = 0; wsi[3] = msize;
      out[out_size - 1] = (float)(n1 + n2);
    }
    for (int d = tid; d < DD; d += 256) out[d] = cls[d] + pos[d];
  } else if (b < 577) {
    int i = (b - 1) * 256 + tid;
    float4 v = ((const float4*)zw)[i];
    bool nz = (v.x != 0.f) | (v.y != 0.f) | (v.z != 0.f) | (v.w != 0.f);
    if (i < DD) nz |= (zb[i] != 0.f);
    if (__any(nz)) {
      if ((tid & 63) == 0) atomicOr(&wsi[2], 1);
    }
  } else if (b < 1153) {
    int i = (b - 577) * 256 + tid;
    float4 v = ((const float4*)proj_w)[i];
    ushort4 u;
    u.x = f2bu(v.x); u.y = f2bu(v.y); u.z = f2bu(v.z); u.w = f2bu(v.w);
    ((ushort4*)Wb)[i] = u;
  } else {
    // pos_pass1: j-direction bicubic conv, pos -> tmp
    int r = b - 1153;                 // [0,1536)
    int x = r / 12, chb = r % 12;
    int d0 = chb * 64;
    float (*lds)[64] = (float(*)[64])shbuf;     // [128][64]
    const float* src = pos + (size_t)(1 + x * 128) * DD + d0;
    for (int it = 0; it < 32; ++it) {
      int idx = it * 256 + tid;
      int y = idx >> 6, d = idx & 63;
      lds[y][d] = src[(size_t)y * DD + d];
    }
    __syncthreads();
    float wb[8];
#pragma unroll
    for (int bb = 0; bb < 8; ++bb) wb[bb] = keys_w(fabsf((float)bb - 3.5f) * 0.5f);
    const int d = tid & 63;
    const int jh = tid >> 6;          // 0..3
    for (int j2 = jh; j2 < 64; j2 += 4) {
      float nj = 0.f, s = 0.f;
#pragma unroll
      for (int bb = 0; bb < 8; ++bb) {
        int y = 2 * j2 - 3 + bb;
        if (y >= 0 && y < 128) { nj += wb[bb]; s += wb[bb] * lds[y][d]; }
      }
      tmp[((size_t)x * 64 + j2) * DD + d0 + d] = __float2bfloat16(s / nj);
    }
  }
}

// =============== K2: stage A rows + FULL Pbuf rows, grid = mpad rows, 192 threads =========
__global__ void k2_stage(const float* __restrict__ img, const int* __restrict__ wsi,
                         const float* __restrict__ pos, const __hip_bfloat16* __restrict__ tmp,
                         __hip_bfloat16* __restrict__ A, __hip_bfloat16* __restrict__ Pbuf,
                         int total, int useSep) {
  const int r = blockIdx.x;
  const int tid = threadIdx.x;            // 0..191
  if (r >= total) {
    ushort4 z = {0, 0, 0, 0};
    *(ushort4*)(A + (size_t)r * DD + tid * 4) = z;
    *(ushort4*)(Pbuf + (size_t)r * DD + tid * 4) = z;
    return;
  }
  const int n1 = wsi[0];
  // ---- A row (bf16 patch) ----
  {
    const int ch = tid >> 6;
    const int rem = tid & 63;
    const int h = rem >> 2;
    const int w4 = rem & 3;
    const int k = ch * 256 + h * 16 + w4 * 4;
    float o0, o1, o2, o3;
    if (r < n1) {
      int cell = wsi[L16_OFF + r];
      int gi = cell >> 7, gj = cell & 127;
      const float* p = img + ((size_t)(ch * IMG) + gi * 16 + h) * IMG + gj * 16 + w4 * 4;
      float4 v = *(const float4*)p;
      o0 = v.x; o1 = v.y; o2 = v.z; o3 = v.w;
    } else {
      int cell = wsi[L32_OFF + (r - n1)];
      int i2 = cell >> 6, j2 = cell & 63;
      const float* p = img + ((size_t)(ch * IMG) + i2 * 32 + h * 2) * IMG + j2 * 32 + w4 * 8;
      float4 a0 = *(const float4*)p;
      float4 a1 = *(const float4*)(p + 4);
      float4 b0 = *(const float4*)(p + IMG);
      float4 b1 = *(const float4*)(p + IMG + 4);
      o0 = 0.25f * (a0.x + a0.y + b0.x + b0.y);
      o1 = 0.25f * (a0.z + a0.w + b0.z + b0.w);
      o2 = 0.25f * (a1.x + a1.y + b1.x + b1.y);
      o3 = 0.25f * (a1.z + a1.w + b1.z + b1.w);
    }
    ushort4 u;
    u.x = f2bu(o0); u.y = f2bu(o1); u.z = f2bu(o2); u.w = f2bu(o3);
    *(ushort4*)(A + (size_t)r * DD + k) = u;
  }
  // ---- Pbuf row: pos16 gather (r<n1) | vertical bicubic from tmp (r>=n1, useSep) ----
  {
    const int d = tid * 4;
    ushort4 pb;
    if (r < n1) {
      int cell = wsi[L16_OFF + r];
      float4 v = *(const float4*)(pos + (size_t)(1 + cell) * DD + d);
      pb.x = f2bu(v.x); pb.y = f2bu(v.y); pb.z = f2bu(v.z); pb.w = f2bu(v.w);
    } else if (useSep) {
      int cell = wsi[L32_OFF + (r - n1)];
      int i2 = cell >> 6, j2 = cell & 63;
      float wi[8]; int xi[8]; float ni = 0.f;
#pragma unroll
      for (int a = 0; a < 8; ++a) {
        float wgt = keys_w(fabsf((float)a - 3.5f) * 0.5f);
        int x = 2 * i2 - 3 + a;
        bool v = (x >= 0 && x < 128);
        wi[a] = v ? wgt : 0.f; xi[a] = v ? x : 0; ni += wi[a];
      }
      float inv = 1.f / ni;
      float s0 = 0.f, s1 = 0.f, s2 = 0.f, s3 = 0.f;
#pragma unroll
      for (int a = 0; a < 8; ++a) {
        if (wi[a] == 0.f) continue;
        ushort4 u = *(const ushort4*)(tmp + ((size_t)xi[a] * 64 + j2) * DD + d);
        s0 += wi[a] * b2f(u.x); s1 += wi[a] * b2f(u.y);
        s2 += wi[a] * b2f(u.z); s3 += wi[a] * b2f(u.w);
      }
      pb.x = f2bu(s0 * inv); pb.y = f2bu(s1 * inv);
      pb.z = f2bu(s2 * inv); pb.w = f2bu(s3 * inv);
    } else {
      pb.x = 0; pb.y = 0; pb.z = 0; pb.w = 0;   // fallback: k4 adds pos32 directly
    }
    *(ushort4*)(Pbuf + (size_t)r * DD + d) = pb;
  }
}

// =============== K3: GEMM (proven R10: 128x128, 4-wave, 4-buf depth-2 counted vmcnt) ======
__global__ __launch_bounds__(256) void gemm_kernel(
    const __hip_bfloat16* __restrict__ A, const __hip_bfloat16* __restrict__ Wb,
    const float* __restrict__ bias, const __hip_bfloat16* __restrict__ Pbuf,
    float* __restrict__ out, int M) {
  __shared__ __hip_bfloat16 As[4][128 * 32];
  __shared__ __hip_bfloat16 Bs[4][128 * 32];
  const int tid = threadIdx.x;
  const int nwg = gridDim.x;
  const int orig = blockIdx.x;
  const int q = nwg >> 3, r8 = nwg & 7;
  const int xcd = orig & 7;
  const int wg = ((xcd < r8) ? xcd * (q + 1) : r8 * (q + 1) + (xcd - r8) * q) + (orig >> 3);
  const int bx = wg % 6;
  const int by = wg / 6;
  const int m0 = by * 128, n0 = bx * 128;
  const int lane = tid & 63, w = tid >> 6;
  const int wr = w >> 1, wc = w & 1;
  f32x4 acc[4][4] = {};

  const int lrow = lane >> 2;
  const int lcol = (lane & 3) * 8;
  const __hip_bfloat16* gA = A + (size_t)(m0 + w * 32 + lrow) * DD + lcol;
  const __hip_bfloat16* gB = Wb + (size_t)(n0 + w * 32 + lrow) * DD + lcol;

#define STAGE(buf, kt)                                           \
  do {                                                           \
    gload16(gA + (kt) * 32, &As[buf][w * 1024]);                 \
    gload16(gA + 16 * DD + (kt) * 32, &As[buf][w * 1024 + 512]); \
    gload16(gB + (kt) * 32, &Bs[buf][w * 1024]);                 \
    gload16(gB + 16 * DD + (kt) * 32, &Bs[buf][w * 1024 + 512]); \
  } while (0)

#define COMPUTE(buf)                                                                         \
  do {                                                                                       \
    bf16x8 af[4], bfr[4];                                                                    \
    _Pragma("unroll") for (int f = 0; f < 4; ++f) {                                          \
      af[f] = *reinterpret_cast<const bf16x8*>(                                              \
          &As[buf][(wr * 64 + f * 16 + (lane & 15)) * 32 + ((lane >> 4) << 3)]);             \
      bfr[f] = *reinterpret_cast<const bf16x8*>(                                             \
          &Bs[buf][(wc * 64 + f * 16 + (lane & 15)) * 32 + ((lane >> 4) << 3)]);             \
    }                                                                                        \
    _Pragma("unroll") for (int fm = 0; fm < 4; ++fm)                                         \
    _Pragma("unroll") for (int fn = 0; fn < 4; ++fn)                                         \
      acc[fm][fn] = __builtin_amdgcn_mfma_f32_16x16x32_bf16(af[fm], bfr[fn], acc[fm][fn],    \
                                                            0, 0, 0);                        \
  } while (0)

  STAGE(0, 0);
  STAGE(1, 1);
#pragma unroll 1
  for (int kt = 0; kt < 22; ++kt) {
    STAGE((kt + 2) & 3, kt + 2);
    asm volatile("s_waitcnt vmcnt(8)" ::: "memory");
    __builtin_amdgcn_s_barrier();
    COMPUTE(kt & 3);
  }
  asm volatile("s_waitcnt vmcnt(4)" ::: "memory");
  __builtin_amdgcn_s_barrier();
  COMPUTE(2);
  asm volatile("s_waitcnt vmcnt(0)" ::: "memory");
  __builtin_amdgcn_s_barrier();
  COMPUTE(3);
#undef STAGE
#undef COMPUTE

#pragma unroll
  for (int fm = 0; fm < 4; ++fm) {
    int mbase = m0 + wr * 64 + fm * 16 + ((lane >> 4) << 2);
#pragma unroll
    for (int r = 0; r < 4; ++r) {
      int m = mbase + r;
      if (m >= M) continue;
      const __hip_bfloat16* pp = Pbuf + (size_t)m * DD;
      float* po = out + (size_t)(1 + m) * DD;
#pragma unroll
      for (int fn = 0; fn < 4; ++fn) {
        int n = n0 + wc * 64 + fn * 16 + (lane & 15);
        po[n] = acc[fm][fn][r] + bias[n] + b2f(*(const unsigned short*)(pp + n));
      }
    }
  }
}

// =============== K4: zc_path (honest, early-exit) [+ pos32_add fallback] ==================
__global__ __launch_bounds__(256) void k4_kernel(
    const float* __restrict__ pos, const int* __restrict__ wsi, float* __restrict__ out,
    int useSep, const float* __restrict__ img, const float* __restrict__ pw,
    const float* __restrict__ pb, const float* __restrict__ aw,
    const float* __restrict__ ab, const float* __restrict__ zw,
    const float* __restrict__ zb) {
  const int b = blockIdx.x;
  const int tid = threadIdx.x;
  const int n1 = wsi[0], n2 = wsi[1];
  const int zcb = useSep ? b : b - NM32;

  if (zcb < 0) {
    int r = b;
    if (r >= n2) return;
    int cell = wsi[L32_OFF + r];
    int i2 = cell >> 6, j2 = cell & 63;
    float wi[8], wj[8]; int xi[8], yj[8]; float ni = 0.f, nj = 0.f;
#pragma unroll
    for (int a = 0; a < 8; ++a) {
      float wgt = keys_w(fabsf((float)a - 3.5f) * 0.5f);
      int x = 2 * i2 - 3 + a;
      bool vx = (x >= 0 && x < 128);
      wi[a] = vx ? wgt : 0.f; xi[a] = vx ? x : 0; ni += wi[a];
      int y = 2 * j2 - 3 + a;
      bool vy = (y >= 0 && y < 128);
      wj[a] = vy ? wgt : 0.f; yj[a] = vy ? y : 0; nj += wj[a];
    }
    float inv = 1.f / (ni * nj);
#pragma unroll
    for (int it = 0; it < 3; ++it) {
      int d = it * 256 + tid;
      float s = 0.f;
#pragma unroll
      for (int a = 0; a < 8; ++a) {
        if (wi[a] == 0.f) continue;
        float si = 0.f;
#pragma unroll
        for (int bb = 0; bb < 8; ++bb) {
          if (wj[bb] == 0.f) continue;
          si += wj[bb] * pos[(size_t)(1 + xi[a] * 128 + yj[bb]) * DD + d];
        }
        s += wi[a] * si;
      }
      out[(size_t)(1 + n1 + r) * DD + d] += s * inv;
    }
  } else {
    if (wsi[2] == 0) return;
    int r = zcb;
    if (r >= n2) return;
    int cell = wsi[L32_OFF + r];
    int i2 = cell >> 6, j2 = cell & 63;
    __shared__ float patch[DD];
    __shared__ float ft[4][DD];
    __shared__ float attnv[DD];
    for (int qq = 0; qq < 4; ++qq) {
      int qh = qq >> 1, qw = qq & 1;
      int gi = 2 * i2 + qh, gj = 2 * j2 + qw;
      for (int it = 0; it < 3; ++it) {
        int k = tid + it * 256;
        int c = k >> 8, h = (k >> 4) & 15, ww = k & 15;
        patch[k] = img[(c * IMG + gi * 16 + h) * IMG + gj * 16 + ww];
      }
      __syncthreads();
      for (int it = 0; it < 3; ++it) {
        int e = tid + it * 256;
        float s = pb[e];
        for (int k = 0; k < DD; ++k) s += patch[k] * pw[(size_t)e * DD + k];
        ft[qq][e] = s;
      }
      __syncthreads();
    }
    for (int it = 0; it < 3; ++it) {
      int d = tid + it * 256;
      float s = ab[d];
      for (int e = 0; e < DD; ++e) {
        const float* awp = aw + ((size_t)d * DD + e) * 4;
        s += ft[0][e] * awp[0] + ft[1][e] * awp[1] + ft[2][e] * awp[2] + ft[3][e] * awp[3];
      }
      attnv[d] = s;
    }
    __syncthreads();
    for (int it = 0; it < 3; ++it) {
      int d = tid + it * 256;
      float s = zb[d];
      for (int e = 0; e < DD; ++e) s += attnv[e] * zw[(size_t)d * DD + e];
      out[(size_t)(1 + n1 + r) * DD + d] += s;
    }
  }
}

extern "C" void kernel_launch(void* const* d_in, const int* in_sizes, int n_in,
                              void* d_out, int out_size, void* d_ws, size_t ws_size,
                              hipStream_t stream) {
  const float* image = (const float*)d_in[0];
  const unsigned char* m16 = (const unsigned char*)d_in[1];
  const unsigned char* m32 = (const unsigned char*)d_in[2];
  const float* proj_w = (const float*)d_in[3];
  const float* proj_b = (const float*)d_in[4];
  const float* cls    = (const float*)d_in[5];
  const float* pos    = (const float*)d_in[6];
  const float* attn_w = (const float*)d_in[7];
  const float* attn_b = (const float*)d_in[8];
  const float* zc_w   = (const float*)d_in[9];
  const float* zc_b   = (const float*)d_in[10];
  float* out = (float*)d_out;

  const int total = (out_size - 1) / DD - 1;          // N1+N2, host-known
  const int mpad = ((total + 127) / 128) * 128;

  int* wsi = (int*)d_ws;
  const size_t offTmp = 82176;
  const size_t tmpB = (size_t)128 * 64 * DD * 2;       // 12.6 MB
  const size_t pbufB = (size_t)mpad * DD * 2;
  const size_t abufB = (size_t)mpad * DD * 2;
  const size_t wB = (size_t)DD * DD * 2;
  bool useSep;
  size_t offP;
  if (ws_size >= offTmp + tmpB + pbufB + abufB + wB) { useSep = true;  offP = offTmp + tmpB; }
  else if (ws_size >= offTmp + pbufB + abufB + wB)   { useSep = false; offP = offTmp; }
  else return;

  __hip_bfloat16* Tmp  = (__hip_bfloat16*)((char*)d_ws + offTmp);
  __hip_bfloat16* Pbuf = (__hip_bfloat16*)((char*)d_ws + offP);
  __hip_bfloat16* Abuf = (__hip_bfloat16*)((char*)d_ws + offP + pbufB);
  __hip_bfloat16* Wbuf = (__hip_bfloat16*)((char*)d_ws + offP + pbufB + abufB);

  int grid1 = 1153 + (useSep ? 1536 : 0);
  k1_kernel<<<grid1, 256, 0, stream>>>(m16, m32, cls, pos, proj_w, zc_w, zc_b, out,
                                       out_size, total, wsi, Wbuf, Tmp);
  k2_stage<<<mpad, 192, 0, stream>>>(image, wsi, pos, Tmp, Abuf, Pbuf, total,
                                     useSep ? 1 : 0);
  int gemm_grid = (mpad / 128) * 6;
  gemm_kernel<<<gemm_grid, 256, 0, stream>>>(Abuf, Wbuf, proj_b, Pbuf, out, total);
  k4_kernel<<<useSep ? NM32 : 2 * NM32, 256, 0, stream>>>(
      pos, wsi, out, useSep ? 1 : 0, image, proj_w, proj_b, attn_w, attn_b, zc_w, zc_b);
}